// Round 16
// baseline (291.558 us; speedup 1.0000x reference)
//
#include <hip/hip_runtime.h>
#include <hip/hip_bf16.h>
#include <cstdint>

// B=4, L=2048, D=1024, H=16, DK=64
// DELTA vs R15 (green, 246.6us) — scheduling only, math byte-identical:
//  1. convert + transposeW1 + transposeW2 fused into one grid-sectioned k_prep.
//  2. maskpack fused into k_gemm<0> as trailing blocks (bid>=1536) so the
//     69MB BW-bound bitpack overlaps the compute-bound QKV GEMM.
// Pipeline: k_prep, GEMM1(+maskpack), flash-attn (8-wave, fixed m=0, ones-MFMA
// denom), GEMM2. Blacklist: AND-mask (R9), exp2f (R14).

typedef __attribute__((ext_vector_type(4))) float f32x4;
typedef __attribute__((ext_vector_type(8))) short s16x8;
typedef __attribute__((ext_vector_type(4))) short s16x4;
typedef __attribute__((ext_vector_type(4))) int   i32x4;

#define AS1 __attribute__((address_space(1)))
#define AS3 __attribute__((address_space(3)))

__device__ __forceinline__ short f2bf(float x) {
  unsigned u = __builtin_bit_cast(unsigned, x);
  unsigned r = u + 0x7fffu + ((u >> 16) & 1u);   // RNE
  return (short)(r >> 16);
}
__device__ __forceinline__ unsigned pack2(float a, float b) {
  // compiler-owned bf16x2 conversion; .x = low word, .y = high word.
  __hip_bfloat162 v = __float22bfloat162_rn(make_float2(a, b));
  unsigned r;
  __builtin_memcpy(&r, &v, 4);
  return r;
}

// ------ fused prep: [0,8192) f32->bf16 convert; [8192,11264) W1 transpose;
// ------ [11264,12288) W2 transpose (transpose+convert to bf16, C x R out)
__global__ __launch_bounds__(256) void k_prep(
    const float* __restrict__ in, short* __restrict__ Xbf,
    const float* __restrict__ W1, short* __restrict__ W1t,
    const float* __restrict__ W2, short* __restrict__ W2t) {
  __shared__ float tile[32][33];
  const int bid = blockIdx.x;
  if (bid < 8192) {                       // convert: 8192*256*4 = 8.39M floats
    int i = bid * 256 + threadIdx.x;
    float4 v = ((const float4*)in)[i];
    s16x4 o;
    o[0] = f2bf(v.x); o[1] = f2bf(v.y); o[2] = f2bf(v.z); o[3] = f2bf(v.w);
    ((s16x4*)Xbf)[i] = o;
    return;
  }
  const float* src; short* dst; int R, C, bx, by;
  if (bid < 11264) { int idx = bid - 8192;  src = W1; dst = W1t; R = 1024; C = 3072; bx = idx % 96; by = idx / 96; }
  else             { int idx = bid - 11264; src = W2; dst = W2t; R = 1024; C = 1024; bx = idx % 32; by = idx / 32; }
  int c0 = bx * 32, r0 = by * 32;
  int tx = threadIdx.x & 31, ty = threadIdx.x >> 5;   // (32,8) roles from 1D
  #pragma unroll
  for (int k = 0; k < 32; k += 8)
    tile[ty + k][tx] = src[(size_t)(r0 + ty + k) * C + c0 + tx];
  __syncthreads();
  #pragma unroll
  for (int k = 0; k < 32; k += 8)
    dst[(size_t)(c0 + ty + k) * R + r0 + tx] = f2bf(tile[tx][ty + k]);
}

// ---------------- bf16 MFMA GEMM, A (MxK) row-major, Bt (NxK) row-major ------
// 1D grid. MODE 0: blocks [0,1536) = QKV projection (m0=(bid&63)*128,
// n0=(bid>>6)*128; cols <1024 (Q) scaled 1/8, cols <2048 -> QKbuf, >=2048 ->
// Vt transposed); blocks [1536, 1536+65536) = mask bitpack via ballot
// (BW-bound, overlaps the compute-bound GEMM blocks). MODE 1: 512 blocks,
// output projection -> f32 out, +bias.
// Staging: global_load_lds width=16, pre-swizzled source chunk, double-buffered
// STAGE(next)->compute(cur)->barrier schedule (attn-proven).
template <int MODE>
__global__ __launch_bounds__(256, 2) void k_gemm(
    const short* __restrict__ A, const short* __restrict__ Bt,
    const float* __restrict__ bias,
    short* __restrict__ outQK, short* __restrict__ outVt,
    float* __restrict__ outF,
    const int* __restrict__ mask, unsigned* __restrict__ mbits, int K, int N) {
  const int bid = blockIdx.x;
  const int tid = threadIdx.x;
  if (MODE == 0 && bid >= 1536) {         // fused mask bitpack
    int i = (bid - 1536) * 256 + tid;
    unsigned long long bal = __ballot(mask[i] != 0);
    int lane = tid & 63;
    if (lane == 0)       mbits[i >> 5] = (unsigned)bal;
    else if (lane == 32) mbits[i >> 5] = (unsigned)(bal >> 32);
    return;
  }
  __shared__ short Ast[2][128 * 64];
  __shared__ short Bst[2][128 * 64];
  const int lane = tid & 63;
  const int wv = tid >> 6;
  const int g = lane >> 4, c = lane & 15;
  const int m0 = (bid & 63) * 128, n0 = (bid >> 6) * 128;
  const int wm = (wv & 1) * 64, wn = (wv >> 1) * 64;

  // staging: wave wv, iter p stages rows [p*32 + wv*8, +8); row&7 == rsub
  const int rsub = lane >> 3;                    // 0..7
  const int cp = (lane & 7) ^ rsub;              // pre-swizzled source chunk
  const short* aSrc = A  + (size_t)(m0 + wv * 8 + rsub) * K + cp * 8;
  const short* bSrc = Bt + (size_t)(n0 + wv * 8 + rsub) * K + cp * 8;

  auto STAGE = [&](int buf, int kt) {
    #pragma unroll
    for (int p = 0; p < 4; ++p) {
      __builtin_amdgcn_global_load_lds(
          (const AS1 void*)(aSrc + (size_t)(p * 32) * K + kt * 64),
          (AS3 void*)&Ast[buf][(p * 32 + wv * 8) * 64], 16, 0, 0);
      __builtin_amdgcn_global_load_lds(
          (const AS1 void*)(bSrc + (size_t)(p * 32) * K + kt * 64),
          (AS3 void*)&Bst[buf][(p * 32 + wv * 8) * 64], 16, 0, 0);
    }
  };

  f32x4 acc[4][4] = {};

  const int nkt = K >> 6;
  STAGE(0, 0);
  __syncthreads();

  #pragma unroll 1
  for (int kt = 0; kt < nkt; ++kt) {
    const int cur = kt & 1;
    if (kt + 1 < nkt) STAGE(cur ^ 1, kt + 1);
    #pragma unroll
    for (int s = 0; s < 2; ++s) {
      s16x8 aF[4], bF[4];
      #pragma unroll
      for (int mi = 0; mi < 4; ++mi) {
        int row = wm + mi * 16 + c;
        aF[mi] = *(const s16x8*)((const char*)&Ast[cur][0] + row * 128 +
                                 ((s * 64 + g * 16) ^ ((row & 7) << 4)));
      }
      #pragma unroll
      for (int ni = 0; ni < 4; ++ni) {
        int row = wn + ni * 16 + c;
        bF[ni] = *(const s16x8*)((const char*)&Bst[cur][0] + row * 128 +
                                 ((s * 64 + g * 16) ^ ((row & 7) << 4)));
      }
      #pragma unroll
      for (int mi = 0; mi < 4; ++mi)
        #pragma unroll
        for (int ni = 0; ni < 4; ++ni)
          acc[mi][ni] = __builtin_amdgcn_mfma_f32_16x16x32_bf16(
              aF[mi], bF[ni], acc[mi][ni], 0, 0, 0);
    }
    __syncthreads();   // drains vmcnt (next tile staged) + all waves done with cur
  }

  #pragma unroll
  for (int mi = 0; mi < 4; ++mi) {
    #pragma unroll
    for (int ni = 0; ni < 4; ++ni) {
      int colg = n0 + wn + ni * 16 + c;
      float bv = bias[colg];
      int rbase = m0 + wm + mi * 16 + 4 * g;   // 4 consecutive rows (4-aligned)
      if (MODE == 0) {
        float sc = (colg < 1024) ? 0.125f : 1.0f;   // fold 1/sqrt(dk) into Q
        if (colg < 2048) {
          #pragma unroll
          for (int r = 0; r < 4; ++r)
            outQK[(size_t)(rbase + r) * 2048 + colg] = f2bf((acc[mi][ni][r] + bv) * sc);
        } else {
          int j = colg - 2048;             // h*64+dk
          int bb = rbase >> 11, lq = rbase & 2047;
          s16x4 pk;
          #pragma unroll
          for (int r = 0; r < 4; ++r) pk[r] = f2bf(acc[mi][ni][r] + bv);
          *(s16x4*)(outVt + (size_t)((bb << 10) + j) * 2048 + lq) = pk;
        }
      } else {
        #pragma unroll
        for (int r = 0; r < 4; ++r)
          outF[(size_t)(rbase + r) * N + colg] = acc[mi][ni][r] + bv;
      }
    }
  }
}

// ---------------- flash attention: 8-wave blocks, shared K/V staging ---------
// Grid (L/128, H, B), 8 waves x 16 q-rows = 128 q-rows/block. K/V tiles staged
// double-buffered via global_load_lds (pre-swizzled source, rule #21); wave wv
// stages rows [wv*8, wv*8+8) = 1 instruction per buffer. S^T = mfma(K,Q):
// lane (c,g) holds S[q=c][k=16t+4g+r]. Fixed m=0 softmax; p_num = bt ?
// __expf(s) : 0 (select form — AND-mask convicted R9; exp2f slow, R14).
// Denominator = ones-MFMA rowsum + popcount(masked) (masked keys each
// contribute exp(0)=1, the torch-quirk semantics).
__global__ __launch_bounds__(512) void k_attn(
    const short* __restrict__ QK, const short* __restrict__ Vt,
    const unsigned* __restrict__ mbits, short* __restrict__ ctxb) {
  __shared__ short Klds[2][64 * 64];
  __shared__ short Vlds[2][64 * 64];
  __shared__ short Plds[8][16 * 64];
  const int tid = threadIdx.x;
  const int lane = tid & 63, wv = tid >> 6;      // wv = 0..7
  const int g = lane >> 4, c = lane & 15;
  const int b = blockIdx.z, h = blockIdx.y;
  const int qr = blockIdx.x * 128 + wv * 16;

  // staging: wave wv stages rows [wv*8, wv*8+8) of each tile (row&7 == rsub)
  const int r0 = wv * 8;
  const int rsub = lane >> 3;                    // 0..7
  const int cp = (lane & 7) ^ rsub;              // pre-swizzled source chunk
  const short* kSrc = QK + (size_t)(b * 2048 + r0 + rsub) * 2048 + 1024 + h * 64 + cp * 8;
  const short* vSrc = Vt + (size_t)((b * 16 + h) * 64 + r0 + rsub) * 2048 + cp * 8;

  auto STAGE = [&](int buf, int k0) {
    __builtin_amdgcn_global_load_lds((const AS1 void*)(kSrc + (size_t)k0 * 2048),
        (AS3 void*)&Klds[buf][r0 * 64], 16, 0, 0);
    __builtin_amdgcn_global_load_lds((const AS1 void*)(vSrc + k0),
        (AS3 void*)&Vlds[buf][r0 * 64], 16, 0, 0);
  };

  s16x8 qf[2];                                    // Q = B-operand fragments
  #pragma unroll
  for (int s = 0; s < 2; ++s)
    qf[s] = *(const s16x8*)(QK + (size_t)(b * 2048 + qr + c) * 2048 +
                            h * 64 + s * 32 + g * 8);

  const unsigned* mptr = mbits + (size_t)(b * 2048 + qr + c) * 64;

  // all-ones bf16 B-operand for the rowsum MFMA
  s16x8 ones;
  #pragma unroll
  for (int i = 0; i < 8; ++i) ones[i] = (short)0x3F80;

  int nm = 0;                       // masked count for q-row c (accumulated)
  f32x4 acc[4] = {};                // ctx[q=4g+r][d=16t+c]
  f32x4 accs = {};                  // rowsum[q=4g+r] of bf16 P (all c equal)
  char* pbase = (char*)&Plds[wv][0];
  const int sw = (c & 7) << 4;

  STAGE(0, 0);
  __syncthreads();

  #pragma unroll 1
  for (int it = 0; it < 32; ++it) {
    const int cur = it & 1;
    const int k0 = it * 64;
    if (it < 31) STAGE(cur ^ 1, k0 + 64);

    // ---- S^T = K Q^T : sf[t][r] = S[q=c][k=16t+4g+r] ----
    const char* kb = (const char*)&Klds[cur][0];
    f32x4 sf[4] = {};
    __builtin_amdgcn_s_setprio(1);
    #pragma unroll
    for (int t = 0; t < 4; ++t)
      #pragma unroll
      for (int s = 0; s < 2; ++s) {
        s16x8 kf = *(const s16x8*)(kb + (16 * t + c) * 128 + ((g * 16 + s * 64) ^ sw));
        sf[t] = __builtin_amdgcn_mfma_f32_16x16x32_bf16(kf, qf[s], sf[t], 0, 0, 0);
      }
    __builtin_amdgcn_s_setprio(0);

    // ---- mask bits for this lane's q-row (q = c) ----
    uint2 wd = *(const uint2*)(mptr + (k0 >> 5));
    nm += 64 - __popc(wd.x) - __popc(wd.y);      // masked keys this tile
    unsigned w0 = wd.x >> (4 * g), w1 = wd.y >> (4 * g);
    // ---- p_num = bt ? exp(s) : 0 ; masked handled via nm in denominator ----
    #pragma unroll
    for (int t = 0; t < 4; ++t) {
      unsigned w = (t < 2) ? w0 : w1;
      int sh = 16 * (t & 1);
      float p[4];
      #pragma unroll
      for (int r = 0; r < 4; ++r) {
        unsigned bt = (w >> (sh + r)) & 1u;
        p[r] = bt ? __expf(sf[t][r]) : 0.0f;     // masked -> 0 in numerator
      }
      unsigned lo = pack2(p[0], p[1]);
      unsigned hi = pack2(p[2], p[3]);
      *(uint2*)(pbase + c * 128 + ((t * 32 + g * 8) ^ sw)) = make_uint2(lo, hi);
    }
    asm volatile("" ::: "memory");   // keep P writes before P reads
    // ---- ctx += P V ; denom += P ones ----
    s16x8 pa[2];
    #pragma unroll
    for (int s = 0; s < 2; ++s)
      pa[s] = *(const s16x8*)(pbase + c * 128 + ((s * 64 + g * 16) ^ sw));
    const char* vb = (const char*)&Vlds[cur][0];
    __builtin_amdgcn_s_setprio(1);
    accs = __builtin_amdgcn_mfma_f32_16x16x32_bf16(pa[0], ones, accs, 0, 0, 0);
    accs = __builtin_amdgcn_mfma_f32_16x16x32_bf16(pa[1], ones, accs, 0, 0, 0);
    #pragma unroll
    for (int t = 0; t < 4; ++t)
      #pragma unroll
      for (int s = 0; s < 2; ++s) {
        s16x8 vf = *(const s16x8*)(vb + (16 * t + c) * 128 + ((g * 16 + s * 64) ^ sw));
        acc[t] = __builtin_amdgcn_mfma_f32_16x16x32_bf16(pa[s], vf, acc[t], 0, 0, 0);
      }
    __builtin_amdgcn_s_setprio(0);
    __syncthreads();   // drains vmcnt (next tile staged) + all waves done with cur
  }

  // ---- epilogue: denom[q=4g+r] = accs[r] + nm(from lane q=4g+r) ----
  float nmf = (float)nm;
  float lv[4];
  #pragma unroll
  for (int r = 0; r < 4; ++r)
    lv[r] = 1.0f / (accs[r] + __shfl(nmf, 4 * g + r));
  #pragma unroll
  for (int t = 0; t < 4; ++t)
    #pragma unroll
    for (int r = 0; r < 4; ++r)
      ctxb[(size_t)(b * 2048 + qr + 4 * g + r) * 1024 + h * 64 + t * 16 + c] =
          f2bf(acc[t][r] * lv[r]);
}

extern "C" void kernel_launch(void* const* d_in, const int* in_sizes, int n_in,
                              void* d_out, int out_size, void* d_ws, size_t ws_size,
                              hipStream_t stream) {
  const float* inputs = (const float*)d_in[0];   // (4,2048,1024) f32
  const int*   mask   = (const int*)  d_in[1];   // (4,2048,2048) int32
  const float* W1     = (const float*)d_in[2];   // (1024,3072) f32
  const float* b1     = (const float*)d_in[3];   // (3072,) f32
  const float* W2     = (const float*)d_in[4];   // (1024,1024) f32
  const float* b2     = (const float*)d_in[5];   // (1024,) f32
  float* out = (float*)d_out;                    // (4,2048,1024) f32

  char* ws = (char*)d_ws;
  short* Xbf = (short*)ws;        ws += (size_t)8192 * 1024 * 2;   // 16.78 MB
  short* W1t = (short*)ws;        ws += (size_t)3072 * 1024 * 2;   //  6.29 MB
  short* W2t = (short*)ws;        ws += (size_t)1024 * 1024 * 2;   //  2.10 MB
  short* QKb = (short*)ws;        ws += (size_t)8192 * 2048 * 2;   // 33.55 MB
  short* Vtb = (short*)ws;        ws += (size_t)4096 * 2048 * 2;   // 16.78 MB
  short* Ctx = (short*)ws;        ws += (size_t)8192 * 1024 * 2;   // 16.78 MB
  unsigned* mbits = (unsigned*)ws; ws += (size_t)4 * 2048 * 64 * 4; // 2.10 MB
  // total ~94.4 MB of d_ws

  k_prep<<<12288, 256, 0, stream>>>(inputs, Xbf, W1, W1t, W2, W2t);
  k_gemm<0><<<1536 + 65536, 256, 0, stream>>>(Xbf, W1t, b1, QKb, Vtb, nullptr,
                                              mask, mbits, 1024, 3072);
  k_attn<<<dim3(16, 16, 4), 512, 0, stream>>>(QKb, Vtb, mbits, Ctx);
  k_gemm<1><<<512, 256, 0, stream>>>(Ctx, W2t, b2, nullptr, nullptr, out,
                                     nullptr, nullptr, 1024, 1024);
}

// Round 17
// 243.594 us; speedup vs baseline: 1.1969x; 1.1969x over previous
//
#include <hip/hip_runtime.h>
#include <hip/hip_bf16.h>
#include <cstdint>

// B=4, L=2048, D=1024, H=16, DK=64
// DELTA vs R16 (regressed): UN-fuse maskpack from k_gemm<0> — fused blocks
// inherited the 64KB LDS footprint -> 2 blocks/CU -> 140us tail (occ 20%).
// Maskpack is again a standalone zero-LDS kernel (full occupancy, ~11us).
// KEPT from R16: k_prep fusion (convert + W1/W2 transpose, 4.2KB LDS).
// Math pipeline = R15 green (246.6us): GEMM1 (Q pre-scaled 1/8, V transposed,
// gload_lds dbuf staging), flash-attn (8-wave, fixed m=0, __expf select-mask,
// ones-MFMA denom + masked popcount), GEMM2. Blacklist: AND-mask, exp2f.

typedef __attribute__((ext_vector_type(4))) float f32x4;
typedef __attribute__((ext_vector_type(8))) short s16x8;
typedef __attribute__((ext_vector_type(4))) short s16x4;
typedef __attribute__((ext_vector_type(4))) int   i32x4;

#define AS1 __attribute__((address_space(1)))
#define AS3 __attribute__((address_space(3)))

__device__ __forceinline__ short f2bf(float x) {
  unsigned u = __builtin_bit_cast(unsigned, x);
  unsigned r = u + 0x7fffu + ((u >> 16) & 1u);   // RNE
  return (short)(r >> 16);
}
__device__ __forceinline__ unsigned pack2(float a, float b) {
  // compiler-owned bf16x2 conversion; .x = low word, .y = high word.
  __hip_bfloat162 v = __float22bfloat162_rn(make_float2(a, b));
  unsigned r;
  __builtin_memcpy(&r, &v, 4);
  return r;
}

// ------ fused prep: [0,8192) f32->bf16 convert; [8192,11264) W1 transpose;
// ------ [11264,12288) W2 transpose (transpose+convert to bf16, C x R out)
__global__ __launch_bounds__(256) void k_prep(
    const float* __restrict__ in, short* __restrict__ Xbf,
    const float* __restrict__ W1, short* __restrict__ W1t,
    const float* __restrict__ W2, short* __restrict__ W2t) {
  __shared__ float tile[32][33];
  const int bid = blockIdx.x;
  if (bid < 8192) {                       // convert: 8192*256*4 = 8.39M floats
    int i = bid * 256 + threadIdx.x;
    float4 v = ((const float4*)in)[i];
    s16x4 o;
    o[0] = f2bf(v.x); o[1] = f2bf(v.y); o[2] = f2bf(v.z); o[3] = f2bf(v.w);
    ((s16x4*)Xbf)[i] = o;
    return;
  }
  const float* src; short* dst; int R, C, bx, by;
  if (bid < 11264) { int idx = bid - 8192;  src = W1; dst = W1t; R = 1024; C = 3072; bx = idx % 96; by = idx / 96; }
  else             { int idx = bid - 11264; src = W2; dst = W2t; R = 1024; C = 1024; bx = idx % 32; by = idx / 32; }
  int c0 = bx * 32, r0 = by * 32;
  int tx = threadIdx.x & 31, ty = threadIdx.x >> 5;   // (32,8) roles from 1D
  #pragma unroll
  for (int k = 0; k < 32; k += 8)
    tile[ty + k][tx] = src[(size_t)(r0 + ty + k) * C + c0 + tx];
  __syncthreads();
  #pragma unroll
  for (int k = 0; k < 32; k += 8)
    dst[(size_t)(c0 + ty + k) * R + r0 + tx] = f2bf(tile[tx][ty + k]);
}

// ---------------- mask (int32 0/1) -> bitmask via ballot (no LDS!) ----------
__global__ __launch_bounds__(256) void k_maskpack(const int* __restrict__ mask,
                                                  unsigned* __restrict__ bits) {
  int i = blockIdx.x * 256 + threadIdx.x;
  unsigned long long bal = __ballot(mask[i] != 0);
  int lane = threadIdx.x & 63;
  if (lane == 0)       bits[i >> 5] = (unsigned)bal;
  else if (lane == 32) bits[i >> 5] = (unsigned)(bal >> 32);
}

// ---------------- bf16 MFMA GEMM, A (MxK) row-major, Bt (NxK) row-major ------
// 1D grid. MODE 0: 1536 blocks = QKV projection (m0=(bid&63)*128,
// n0=(bid>>6)*128; cols <1024 (Q) scaled 1/8, cols <2048 -> QKbuf, >=2048 ->
// Vt transposed). MODE 1: 512 blocks, output projection -> f32 out, +bias.
// Staging: global_load_lds width=16, pre-swizzled source chunk, double-buffered
// STAGE(next)->compute(cur)->barrier schedule (attn-proven).
template <int MODE>
__global__ __launch_bounds__(256, 2) void k_gemm(
    const short* __restrict__ A, const short* __restrict__ Bt,
    const float* __restrict__ bias,
    short* __restrict__ outQK, short* __restrict__ outVt,
    float* __restrict__ outF, int K, int N) {
  __shared__ short Ast[2][128 * 64];
  __shared__ short Bst[2][128 * 64];
  const int bid = blockIdx.x;
  const int tid = threadIdx.x;
  const int lane = tid & 63;
  const int wv = tid >> 6;
  const int g = lane >> 4, c = lane & 15;
  const int m0 = (bid & 63) * 128, n0 = (bid >> 6) * 128;
  const int wm = (wv & 1) * 64, wn = (wv >> 1) * 64;

  // staging: wave wv, iter p stages rows [p*32 + wv*8, +8); row&7 == rsub
  const int rsub = lane >> 3;                    // 0..7
  const int cp = (lane & 7) ^ rsub;              // pre-swizzled source chunk
  const short* aSrc = A  + (size_t)(m0 + wv * 8 + rsub) * K + cp * 8;
  const short* bSrc = Bt + (size_t)(n0 + wv * 8 + rsub) * K + cp * 8;

  auto STAGE = [&](int buf, int kt) {
    #pragma unroll
    for (int p = 0; p < 4; ++p) {
      __builtin_amdgcn_global_load_lds(
          (const AS1 void*)(aSrc + (size_t)(p * 32) * K + kt * 64),
          (AS3 void*)&Ast[buf][(p * 32 + wv * 8) * 64], 16, 0, 0);
      __builtin_amdgcn_global_load_lds(
          (const AS1 void*)(bSrc + (size_t)(p * 32) * K + kt * 64),
          (AS3 void*)&Bst[buf][(p * 32 + wv * 8) * 64], 16, 0, 0);
    }
  };

  f32x4 acc[4][4] = {};

  const int nkt = K >> 6;
  STAGE(0, 0);
  __syncthreads();

  #pragma unroll 1
  for (int kt = 0; kt < nkt; ++kt) {
    const int cur = kt & 1;
    if (kt + 1 < nkt) STAGE(cur ^ 1, kt + 1);
    #pragma unroll
    for (int s = 0; s < 2; ++s) {
      s16x8 aF[4], bF[4];
      #pragma unroll
      for (int mi = 0; mi < 4; ++mi) {
        int row = wm + mi * 16 + c;
        aF[mi] = *(const s16x8*)((const char*)&Ast[cur][0] + row * 128 +
                                 ((s * 64 + g * 16) ^ ((row & 7) << 4)));
      }
      #pragma unroll
      for (int ni = 0; ni < 4; ++ni) {
        int row = wn + ni * 16 + c;
        bF[ni] = *(const s16x8*)((const char*)&Bst[cur][0] + row * 128 +
                                 ((s * 64 + g * 16) ^ ((row & 7) << 4)));
      }
      #pragma unroll
      for (int mi = 0; mi < 4; ++mi)
        #pragma unroll
        for (int ni = 0; ni < 4; ++ni)
          acc[mi][ni] = __builtin_amdgcn_mfma_f32_16x16x32_bf16(
              aF[mi], bF[ni], acc[mi][ni], 0, 0, 0);
    }
    __syncthreads();   // drains vmcnt (next tile staged) + all waves done with cur
  }

  #pragma unroll
  for (int mi = 0; mi < 4; ++mi) {
    #pragma unroll
    for (int ni = 0; ni < 4; ++ni) {
      int colg = n0 + wn + ni * 16 + c;
      float bv = bias[colg];
      int rbase = m0 + wm + mi * 16 + 4 * g;   // 4 consecutive rows (4-aligned)
      if (MODE == 0) {
        float sc = (colg < 1024) ? 0.125f : 1.0f;   // fold 1/sqrt(dk) into Q
        if (colg < 2048) {
          #pragma unroll
          for (int r = 0; r < 4; ++r)
            outQK[(size_t)(rbase + r) * 2048 + colg] = f2bf((acc[mi][ni][r] + bv) * sc);
        } else {
          int j = colg - 2048;             // h*64+dk
          int bb = rbase >> 11, lq = rbase & 2047;
          s16x4 pk;
          #pragma unroll
          for (int r = 0; r < 4; ++r) pk[r] = f2bf(acc[mi][ni][r] + bv);
          *(s16x4*)(outVt + (size_t)((bb << 10) + j) * 2048 + lq) = pk;
        }
      } else {
        #pragma unroll
        for (int r = 0; r < 4; ++r)
          outF[(size_t)(rbase + r) * N + colg] = acc[mi][ni][r] + bv;
      }
    }
  }
}

// ---------------- flash attention: 8-wave blocks, shared K/V staging ---------
// Grid (L/128, H, B), 8 waves x 16 q-rows = 128 q-rows/block. K/V tiles staged
// double-buffered via global_load_lds (pre-swizzled source, rule #21); wave wv
// stages rows [wv*8, wv*8+8) = 1 instruction per buffer. S^T = mfma(K,Q):
// lane (c,g) holds S[q=c][k=16t+4g+r]. Fixed m=0 softmax; p_num = bt ?
// __expf(s) : 0 (select form — AND-mask convicted R9; exp2f slow, R14).
// Denominator = ones-MFMA rowsum + popcount(masked) (masked keys each
// contribute exp(0)=1, the torch-quirk semantics).
__global__ __launch_bounds__(512) void k_attn(
    const short* __restrict__ QK, const short* __restrict__ Vt,
    const unsigned* __restrict__ mbits, short* __restrict__ ctxb) {
  __shared__ short Klds[2][64 * 64];
  __shared__ short Vlds[2][64 * 64];
  __shared__ short Plds[8][16 * 64];
  const int tid = threadIdx.x;
  const int lane = tid & 63, wv = tid >> 6;      // wv = 0..7
  const int g = lane >> 4, c = lane & 15;
  const int b = blockIdx.z, h = blockIdx.y;
  const int qr = blockIdx.x * 128 + wv * 16;

  // staging: wave wv stages rows [wv*8, wv*8+8) of each tile (row&7 == rsub)
  const int r0 = wv * 8;
  const int rsub = lane >> 3;                    // 0..7
  const int cp = (lane & 7) ^ rsub;              // pre-swizzled source chunk
  const short* kSrc = QK + (size_t)(b * 2048 + r0 + rsub) * 2048 + 1024 + h * 64 + cp * 8;
  const short* vSrc = Vt + (size_t)((b * 16 + h) * 64 + r0 + rsub) * 2048 + cp * 8;

  auto STAGE = [&](int buf, int k0) {
    __builtin_amdgcn_global_load_lds((const AS1 void*)(kSrc + (size_t)k0 * 2048),
        (AS3 void*)&Klds[buf][r0 * 64], 16, 0, 0);
    __builtin_amdgcn_global_load_lds((const AS1 void*)(vSrc + k0),
        (AS3 void*)&Vlds[buf][r0 * 64], 16, 0, 0);
  };

  s16x8 qf[2];                                    // Q = B-operand fragments
  #pragma unroll
  for (int s = 0; s < 2; ++s)
    qf[s] = *(const s16x8*)(QK + (size_t)(b * 2048 + qr + c) * 2048 +
                            h * 64 + s * 32 + g * 8);

  const unsigned* mptr = mbits + (size_t)(b * 2048 + qr + c) * 64;

  // all-ones bf16 B-operand for the rowsum MFMA
  s16x8 ones;
  #pragma unroll
  for (int i = 0; i < 8; ++i) ones[i] = (short)0x3F80;

  int nm = 0;                       // masked count for q-row c (accumulated)
  f32x4 acc[4] = {};                // ctx[q=4g+r][d=16t+c]
  f32x4 accs = {};                  // rowsum[q=4g+r] of bf16 P (all c equal)
  char* pbase = (char*)&Plds[wv][0];
  const int sw = (c & 7) << 4;

  STAGE(0, 0);
  __syncthreads();

  #pragma unroll 1
  for (int it = 0; it < 32; ++it) {
    const int cur = it & 1;
    const int k0 = it * 64;
    if (it < 31) STAGE(cur ^ 1, k0 + 64);

    // ---- S^T = K Q^T : sf[t][r] = S[q=c][k=16t+4g+r] ----
    const char* kb = (const char*)&Klds[cur][0];
    f32x4 sf[4] = {};
    __builtin_amdgcn_s_setprio(1);
    #pragma unroll
    for (int t = 0; t < 4; ++t)
      #pragma unroll
      for (int s = 0; s < 2; ++s) {
        s16x8 kf = *(const s16x8*)(kb + (16 * t + c) * 128 + ((g * 16 + s * 64) ^ sw));
        sf[t] = __builtin_amdgcn_mfma_f32_16x16x32_bf16(kf, qf[s], sf[t], 0, 0, 0);
      }
    __builtin_amdgcn_s_setprio(0);

    // ---- mask bits for this lane's q-row (q = c) ----
    uint2 wd = *(const uint2*)(mptr + (k0 >> 5));
    nm += 64 - __popc(wd.x) - __popc(wd.y);      // masked keys this tile
    unsigned w0 = wd.x >> (4 * g), w1 = wd.y >> (4 * g);
    // ---- p_num = bt ? exp(s) : 0 ; masked handled via nm in denominator ----
    #pragma unroll
    for (int t = 0; t < 4; ++t) {
      unsigned w = (t < 2) ? w0 : w1;
      int sh = 16 * (t & 1);
      float p[4];
      #pragma unroll
      for (int r = 0; r < 4; ++r) {
        unsigned bt = (w >> (sh + r)) & 1u;
        p[r] = bt ? __expf(sf[t][r]) : 0.0f;     // masked -> 0 in numerator
      }
      unsigned lo = pack2(p[0], p[1]);
      unsigned hi = pack2(p[2], p[3]);
      *(uint2*)(pbase + c * 128 + ((t * 32 + g * 8) ^ sw)) = make_uint2(lo, hi);
    }
    asm volatile("" ::: "memory");   // keep P writes before P reads
    // ---- ctx += P V ; denom += P ones ----
    s16x8 pa[2];
    #pragma unroll
    for (int s = 0; s < 2; ++s)
      pa[s] = *(const s16x8*)(pbase + c * 128 + ((s * 64 + g * 16) ^ sw));
    const char* vb = (const char*)&Vlds[cur][0];
    __builtin_amdgcn_s_setprio(1);
    accs = __builtin_amdgcn_mfma_f32_16x16x32_bf16(pa[0], ones, accs, 0, 0, 0);
    accs = __builtin_amdgcn_mfma_f32_16x16x32_bf16(pa[1], ones, accs, 0, 0, 0);
    #pragma unroll
    for (int t = 0; t < 4; ++t)
      #pragma unroll
      for (int s = 0; s < 2; ++s) {
        s16x8 vf = *(const s16x8*)(vb + (16 * t + c) * 128 + ((g * 16 + s * 64) ^ sw));
        acc[t] = __builtin_amdgcn_mfma_f32_16x16x32_bf16(pa[s], vf, acc[t], 0, 0, 0);
      }
    __builtin_amdgcn_s_setprio(0);
    __syncthreads();   // drains vmcnt (next tile staged) + all waves done with cur
  }

  // ---- epilogue: denom[q=4g+r] = accs[r] + nm(from lane q=4g+r) ----
  float nmf = (float)nm;
  float lv[4];
  #pragma unroll
  for (int r = 0; r < 4; ++r)
    lv[r] = 1.0f / (accs[r] + __shfl(nmf, 4 * g + r));
  #pragma unroll
  for (int t = 0; t < 4; ++t)
    #pragma unroll
    for (int r = 0; r < 4; ++r)
      ctxb[(size_t)(b * 2048 + qr + 4 * g + r) * 1024 + h * 64 + t * 16 + c] =
          f2bf(acc[t][r] * lv[r]);
}

extern "C" void kernel_launch(void* const* d_in, const int* in_sizes, int n_in,
                              void* d_out, int out_size, void* d_ws, size_t ws_size,
                              hipStream_t stream) {
  const float* inputs = (const float*)d_in[0];   // (4,2048,1024) f32
  const int*   mask   = (const int*)  d_in[1];   // (4,2048,2048) int32
  const float* W1     = (const float*)d_in[2];   // (1024,3072) f32
  const float* b1     = (const float*)d_in[3];   // (3072,) f32
  const float* W2     = (const float*)d_in[4];   // (1024,1024) f32
  const float* b2     = (const float*)d_in[5];   // (1024,) f32
  float* out = (float*)d_out;                    // (4,2048,1024) f32

  char* ws = (char*)d_ws;
  short* Xbf = (short*)ws;        ws += (size_t)8192 * 1024 * 2;   // 16.78 MB
  short* W1t = (short*)ws;        ws += (size_t)3072 * 1024 * 2;   //  6.29 MB
  short* W2t = (short*)ws;        ws += (size_t)1024 * 1024 * 2;   //  2.10 MB
  short* QKb = (short*)ws;        ws += (size_t)8192 * 2048 * 2;   // 33.55 MB
  short* Vtb = (short*)ws;        ws += (size_t)4096 * 2048 * 2;   // 16.78 MB
  short* Ctx = (short*)ws;        ws += (size_t)8192 * 1024 * 2;   // 16.78 MB
  unsigned* mbits = (unsigned*)ws; ws += (size_t)4 * 2048 * 64 * 4; // 2.10 MB
  // total ~94.4 MB of d_ws

  k_prep<<<12288, 256, 0, stream>>>(inputs, Xbf, W1, W1t, W2, W2t);
  k_gemm<0><<<1536, 256, 0, stream>>>(Xbf, W1t, b1, QKb, Vtb, nullptr,
                                      1024, 3072);
  k_maskpack<<<65536, 256, 0, stream>>>(mask, mbits);
  k_attn<<<dim3(16, 16, 4), 512, 0, stream>>>(QKb, Vtb, mbits, Ctx);
  k_gemm<1><<<512, 256, 0, stream>>>(Ctx, W2t, b2, nullptr, nullptr, out,
                                     1024, 1024);
}

// Round 18
// 236.624 us; speedup vs baseline: 1.2322x; 1.0295x over previous
//
#include <hip/hip_runtime.h>
#include <hip/hip_bf16.h>
#include <cstdint>

// B=4, L=2048, D=1024, H=16, DK=64
// DELTA vs R17 (green, 243.6us) — k_attn only: K-tile single-buffered.
// K[cur] is fully consumed by QK^T at iter top, so: QK^T -> barrier A ->
// STAGE_K(next)+STAGE_V(vnxt) -> softmax+PV -> barrier B (drains stages).
// LDS 48KB -> 40KB => 4 blocks/CU (was 3), occupancy ~51%->~66%.
// Mask load hoisted above QK^T so its waitcnt doesn't drain the stage queue.
// Math byte-identical. Blacklist: AND-mask (R9), exp2f (R14), LDS-fat fusion (R16).

typedef __attribute__((ext_vector_type(4))) float f32x4;
typedef __attribute__((ext_vector_type(8))) short s16x8;
typedef __attribute__((ext_vector_type(4))) short s16x4;
typedef __attribute__((ext_vector_type(4))) int   i32x4;

#define AS1 __attribute__((address_space(1)))
#define AS3 __attribute__((address_space(3)))

__device__ __forceinline__ short f2bf(float x) {
  unsigned u = __builtin_bit_cast(unsigned, x);
  unsigned r = u + 0x7fffu + ((u >> 16) & 1u);   // RNE
  return (short)(r >> 16);
}
__device__ __forceinline__ unsigned pack2(float a, float b) {
  // compiler-owned bf16x2 conversion; .x = low word, .y = high word.
  __hip_bfloat162 v = __float22bfloat162_rn(make_float2(a, b));
  unsigned r;
  __builtin_memcpy(&r, &v, 4);
  return r;
}

// ------ fused prep: [0,8192) f32->bf16 convert; [8192,11264) W1 transpose;
// ------ [11264,12288) W2 transpose (transpose+convert to bf16, C x R out)
__global__ __launch_bounds__(256) void k_prep(
    const float* __restrict__ in, short* __restrict__ Xbf,
    const float* __restrict__ W1, short* __restrict__ W1t,
    const float* __restrict__ W2, short* __restrict__ W2t) {
  __shared__ float tile[32][33];
  const int bid = blockIdx.x;
  if (bid < 8192) {                       // convert: 8192*256*4 = 8.39M floats
    int i = bid * 256 + threadIdx.x;
    float4 v = ((const float4*)in)[i];
    s16x4 o;
    o[0] = f2bf(v.x); o[1] = f2bf(v.y); o[2] = f2bf(v.z); o[3] = f2bf(v.w);
    ((s16x4*)Xbf)[i] = o;
    return;
  }
  const float* src; short* dst; int R, C, bx, by;
  if (bid < 11264) { int idx = bid - 8192;  src = W1; dst = W1t; R = 1024; C = 3072; bx = idx % 96; by = idx / 96; }
  else             { int idx = bid - 11264; src = W2; dst = W2t; R = 1024; C = 1024; bx = idx % 32; by = idx / 32; }
  int c0 = bx * 32, r0 = by * 32;
  int tx = threadIdx.x & 31, ty = threadIdx.x >> 5;   // (32,8) roles from 1D
  #pragma unroll
  for (int k = 0; k < 32; k += 8)
    tile[ty + k][tx] = src[(size_t)(r0 + ty + k) * C + c0 + tx];
  __syncthreads();
  #pragma unroll
  for (int k = 0; k < 32; k += 8)
    dst[(size_t)(c0 + ty + k) * R + r0 + tx] = f2bf(tile[tx][ty + k]);
}

// ---------------- mask (int32 0/1) -> bitmask via ballot (no LDS!) ----------
__global__ __launch_bounds__(256) void k_maskpack(const int* __restrict__ mask,
                                                  unsigned* __restrict__ bits) {
  int i = blockIdx.x * 256 + threadIdx.x;
  unsigned long long bal = __ballot(mask[i] != 0);
  int lane = threadIdx.x & 63;
  if (lane == 0)       bits[i >> 5] = (unsigned)bal;
  else if (lane == 32) bits[i >> 5] = (unsigned)(bal >> 32);
}

// ---------------- bf16 MFMA GEMM, A (MxK) row-major, Bt (NxK) row-major ------
// 1D grid. MODE 0: 1536 blocks = QKV projection (m0=(bid&63)*128,
// n0=(bid>>6)*128; cols <1024 (Q) scaled 1/8, cols <2048 -> QKbuf, >=2048 ->
// Vt transposed). MODE 1: 512 blocks, output projection -> f32 out, +bias.
// Staging: global_load_lds width=16, pre-swizzled source chunk, double-buffered
// STAGE(next)->compute(cur)->barrier schedule (attn-proven).
template <int MODE>
__global__ __launch_bounds__(256, 2) void k_gemm(
    const short* __restrict__ A, const short* __restrict__ Bt,
    const float* __restrict__ bias,
    short* __restrict__ outQK, short* __restrict__ outVt,
    float* __restrict__ outF, int K, int N) {
  __shared__ short Ast[2][128 * 64];
  __shared__ short Bst[2][128 * 64];
  const int bid = blockIdx.x;
  const int tid = threadIdx.x;
  const int lane = tid & 63;
  const int wv = tid >> 6;
  const int g = lane >> 4, c = lane & 15;
  const int m0 = (bid & 63) * 128, n0 = (bid >> 6) * 128;
  const int wm = (wv & 1) * 64, wn = (wv >> 1) * 64;

  // staging: wave wv, iter p stages rows [p*32 + wv*8, +8); row&7 == rsub
  const int rsub = lane >> 3;                    // 0..7
  const int cp = (lane & 7) ^ rsub;              // pre-swizzled source chunk
  const short* aSrc = A  + (size_t)(m0 + wv * 8 + rsub) * K + cp * 8;
  const short* bSrc = Bt + (size_t)(n0 + wv * 8 + rsub) * K + cp * 8;

  auto STAGE = [&](int buf, int kt) {
    #pragma unroll
    for (int p = 0; p < 4; ++p) {
      __builtin_amdgcn_global_load_lds(
          (const AS1 void*)(aSrc + (size_t)(p * 32) * K + kt * 64),
          (AS3 void*)&Ast[buf][(p * 32 + wv * 8) * 64], 16, 0, 0);
      __builtin_amdgcn_global_load_lds(
          (const AS1 void*)(bSrc + (size_t)(p * 32) * K + kt * 64),
          (AS3 void*)&Bst[buf][(p * 32 + wv * 8) * 64], 16, 0, 0);
    }
  };

  f32x4 acc[4][4] = {};

  const int nkt = K >> 6;
  STAGE(0, 0);
  __syncthreads();

  #pragma unroll 1
  for (int kt = 0; kt < nkt; ++kt) {
    const int cur = kt & 1;
    if (kt + 1 < nkt) STAGE(cur ^ 1, kt + 1);
    #pragma unroll
    for (int s = 0; s < 2; ++s) {
      s16x8 aF[4], bF[4];
      #pragma unroll
      for (int mi = 0; mi < 4; ++mi) {
        int row = wm + mi * 16 + c;
        aF[mi] = *(const s16x8*)((const char*)&Ast[cur][0] + row * 128 +
                                 ((s * 64 + g * 16) ^ ((row & 7) << 4)));
      }
      #pragma unroll
      for (int ni = 0; ni < 4; ++ni) {
        int row = wn + ni * 16 + c;
        bF[ni] = *(const s16x8*)((const char*)&Bst[cur][0] + row * 128 +
                                 ((s * 64 + g * 16) ^ ((row & 7) << 4)));
      }
      #pragma unroll
      for (int mi = 0; mi < 4; ++mi)
        #pragma unroll
        for (int ni = 0; ni < 4; ++ni)
          acc[mi][ni] = __builtin_amdgcn_mfma_f32_16x16x32_bf16(
              aF[mi], bF[ni], acc[mi][ni], 0, 0, 0);
    }
    __syncthreads();   // drains vmcnt (next tile staged) + all waves done with cur
  }

  #pragma unroll
  for (int mi = 0; mi < 4; ++mi) {
    #pragma unroll
    for (int ni = 0; ni < 4; ++ni) {
      int colg = n0 + wn + ni * 16 + c;
      float bv = bias[colg];
      int rbase = m0 + wm + mi * 16 + 4 * g;   // 4 consecutive rows (4-aligned)
      if (MODE == 0) {
        float sc = (colg < 1024) ? 0.125f : 1.0f;   // fold 1/sqrt(dk) into Q
        if (colg < 2048) {
          #pragma unroll
          for (int r = 0; r < 4; ++r)
            outQK[(size_t)(rbase + r) * 2048 + colg] = f2bf((acc[mi][ni][r] + bv) * sc);
        } else {
          int j = colg - 2048;             // h*64+dk
          int bb = rbase >> 11, lq = rbase & 2047;
          s16x4 pk;
          #pragma unroll
          for (int r = 0; r < 4; ++r) pk[r] = f2bf(acc[mi][ni][r] + bv);
          *(s16x4*)(outVt + (size_t)((bb << 10) + j) * 2048 + lq) = pk;
        }
      } else {
        #pragma unroll
        for (int r = 0; r < 4; ++r)
          outF[(size_t)(rbase + r) * N + colg] = acc[mi][ni][r] + bv;
      }
    }
  }
}

// ---------------- flash attention: 8-wave blocks, K single-buffered ----------
// Grid (L/128, H, B), 8 waves x 16 q-rows = 128 q-rows/block. K is consumed at
// iter top (QK^T) -> single-buffered: QK^T -> barrier A -> STAGE_K(next) +
// STAGE_V(vnxt) -> softmax/P/PV -> barrier B (drains stages). V stays
// double-buffered. LDS 40KB => 4 blocks/CU. Mask load hoisted above QK^T so
// its waitcnt keeps the stage queue in flight. S^T = mfma(K,Q): lane (c,g)
// holds S[q=c][k=16t+4g+r]. Fixed m=0 softmax; p_num = bt ? __expf(s) : 0.
// Denominator = ones-MFMA rowsum + popcount(masked) (torch-quirk semantics).
__global__ __launch_bounds__(512) void k_attn(
    const short* __restrict__ QK, const short* __restrict__ Vt,
    const unsigned* __restrict__ mbits, short* __restrict__ ctxb) {
  __shared__ short Klds[64 * 64];        // single-buffered (8 KB)
  __shared__ short Vlds[2][64 * 64];     // double-buffered (16 KB)
  __shared__ short Plds[8][16 * 64];     // per-wave P (16 KB)
  const int tid = threadIdx.x;
  const int lane = tid & 63, wv = tid >> 6;      // wv = 0..7
  const int g = lane >> 4, c = lane & 15;
  const int b = blockIdx.z, h = blockIdx.y;
  const int qr = blockIdx.x * 128 + wv * 16;

  // staging: wave wv stages rows [wv*8, wv*8+8) of each tile (row&7 == rsub)
  const int r0 = wv * 8;
  const int rsub = lane >> 3;                    // 0..7
  const int cp = (lane & 7) ^ rsub;              // pre-swizzled source chunk
  const short* kSrc = QK + (size_t)(b * 2048 + r0 + rsub) * 2048 + 1024 + h * 64 + cp * 8;
  const short* vSrc = Vt + (size_t)((b * 16 + h) * 64 + r0 + rsub) * 2048 + cp * 8;

  auto STAGE_K = [&](int k0) {
    __builtin_amdgcn_global_load_lds((const AS1 void*)(kSrc + (size_t)k0 * 2048),
        (AS3 void*)&Klds[r0 * 64], 16, 0, 0);
  };
  auto STAGE_V = [&](int buf, int k0) {
    __builtin_amdgcn_global_load_lds((const AS1 void*)(vSrc + k0),
        (AS3 void*)&Vlds[buf][r0 * 64], 16, 0, 0);
  };

  s16x8 qf[2];                                    // Q = B-operand fragments
  #pragma unroll
  for (int s = 0; s < 2; ++s)
    qf[s] = *(const s16x8*)(QK + (size_t)(b * 2048 + qr + c) * 2048 +
                            h * 64 + s * 32 + g * 8);

  const unsigned* mptr = mbits + (size_t)(b * 2048 + qr + c) * 64;

  // all-ones bf16 B-operand for the rowsum MFMA
  s16x8 ones;
  #pragma unroll
  for (int i = 0; i < 8; ++i) ones[i] = (short)0x3F80;

  int nm = 0;                       // masked count for q-row c (accumulated)
  f32x4 acc[4] = {};                // ctx[q=4g+r][d=16t+c]
  f32x4 accs = {};                  // rowsum[q=4g+r] of bf16 P (all c equal)
  char* pbase = (char*)&Plds[wv][0];
  const int sw = (c & 7) << 4;

  STAGE_K(0);
  STAGE_V(0, 0);
  __syncthreads();

  #pragma unroll 1
  for (int it = 0; it < 32; ++it) {
    const int vcur = it & 1;
    const int k0 = it * 64;

    // ---- mask bits first: consumer waits vmcnt(2), stages stay in flight ----
    uint2 wd = *(const uint2*)(mptr + (k0 >> 5));

    // ---- S^T = K Q^T : sf[t][r] = S[q=c][k=16t+4g+r] ----
    const char* kb = (const char*)&Klds[0];
    f32x4 sf[4] = {};
    __builtin_amdgcn_s_setprio(1);
    #pragma unroll
    for (int t = 0; t < 4; ++t)
      #pragma unroll
      for (int s = 0; s < 2; ++s) {
        s16x8 kf = *(const s16x8*)(kb + (16 * t + c) * 128 + ((g * 16 + s * 64) ^ sw));
        sf[t] = __builtin_amdgcn_mfma_f32_16x16x32_bf16(kf, qf[s], sf[t], 0, 0, 0);
      }
    __builtin_amdgcn_s_setprio(0);

    __syncthreads();   // barrier A: all waves done reading Klds (nothing to drain)
    if (it < 31) {
      STAGE_K(k0 + 64);             // overwrite Klds: safe, post-barrier-A
      STAGE_V(vcur ^ 1, k0 + 64);
    }

    nm += 64 - __popc(wd.x) - __popc(wd.y);      // masked keys this tile
    unsigned w0 = wd.x >> (4 * g), w1 = wd.y >> (4 * g);
    // ---- p_num = bt ? exp(s) : 0 ; masked handled via nm in denominator ----
    #pragma unroll
    for (int t = 0; t < 4; ++t) {
      unsigned w = (t < 2) ? w0 : w1;
      int sh = 16 * (t & 1);
      float p[4];
      #pragma unroll
      for (int r = 0; r < 4; ++r) {
        unsigned bt = (w >> (sh + r)) & 1u;
        p[r] = bt ? __expf(sf[t][r]) : 0.0f;     // masked -> 0 in numerator
      }
      unsigned lo = pack2(p[0], p[1]);
      unsigned hi = pack2(p[2], p[3]);
      *(uint2*)(pbase + c * 128 + ((t * 32 + g * 8) ^ sw)) = make_uint2(lo, hi);
    }
    asm volatile("" ::: "memory");   // keep P writes before P reads
    // ---- ctx += P V ; denom += P ones ----
    s16x8 pa[2];
    #pragma unroll
    for (int s = 0; s < 2; ++s)
      pa[s] = *(const s16x8*)(pbase + c * 128 + ((s * 64 + g * 16) ^ sw));
    const char* vb = (const char*)&Vlds[vcur][0];
    __builtin_amdgcn_s_setprio(1);
    accs = __builtin_amdgcn_mfma_f32_16x16x32_bf16(pa[0], ones, accs, 0, 0, 0);
    accs = __builtin_amdgcn_mfma_f32_16x16x32_bf16(pa[1], ones, accs, 0, 0, 0);
    #pragma unroll
    for (int t = 0; t < 4; ++t)
      #pragma unroll
      for (int s = 0; s < 2; ++s) {
        s16x8 vf = *(const s16x8*)(vb + (16 * t + c) * 128 + ((g * 16 + s * 64) ^ sw));
        acc[t] = __builtin_amdgcn_mfma_f32_16x16x32_bf16(pa[s], vf, acc[t], 0, 0, 0);
      }
    __builtin_amdgcn_s_setprio(0);
    __syncthreads();   // barrier B: drains K/V stages; all waves done with vcur
  }

  // ---- epilogue: denom[q=4g+r] = accs[r] + nm(from lane q=4g+r) ----
  float nmf = (float)nm;
  float lv[4];
  #pragma unroll
  for (int r = 0; r < 4; ++r)
    lv[r] = 1.0f / (accs[r] + __shfl(nmf, 4 * g + r));
  #pragma unroll
  for (int t = 0; t < 4; ++t)
    #pragma unroll
    for (int r = 0; r < 4; ++r)
      ctxb[(size_t)(b * 2048 + qr + 4 * g + r) * 1024 + h * 64 + t * 16 + c] =
          f2bf(acc[t][r] * lv[r]);
}

extern "C" void kernel_launch(void* const* d_in, const int* in_sizes, int n_in,
                              void* d_out, int out_size, void* d_ws, size_t ws_size,
                              hipStream_t stream) {
  const float* inputs = (const float*)d_in[0];   // (4,2048,1024) f32
  const int*   mask   = (const int*)  d_in[1];   // (4,2048,2048) int32
  const float* W1     = (const float*)d_in[2];   // (1024,3072) f32
  const float* b1     = (const float*)d_in[3];   // (3072,) f32
  const float* W2     = (const float*)d_in[4];   // (1024,1024) f32
  const float* b2     = (const float*)d_in[5];   // (1024,) f32
  float* out = (float*)d_out;                    // (4,2048,1024) f32

  char* ws = (char*)d_ws;
  short* Xbf = (short*)ws;        ws += (size_t)8192 * 1024 * 2;   // 16.78 MB
  short* W1t = (short*)ws;        ws += (size_t)3072 * 1024 * 2;   //  6.29 MB
  short* W2t = (short*)ws;        ws += (size_t)1024 * 1024 * 2;   //  2.10 MB
  short* QKb = (short*)ws;        ws += (size_t)8192 * 2048 * 2;   // 33.55 MB
  short* Vtb = (short*)ws;        ws += (size_t)4096 * 2048 * 2;   // 16.78 MB
  short* Ctx = (short*)ws;        ws += (size_t)8192 * 1024 * 2;   // 16.78 MB
  unsigned* mbits = (unsigned*)ws; ws += (size_t)4 * 2048 * 64 * 4; // 2.10 MB
  // total ~94.4 MB of d_ws

  k_prep<<<12288, 256, 0, stream>>>(inputs, Xbf, W1, W1t, W2, W2t);
  k_gemm<0><<<1536, 256, 0, stream>>>(Xbf, W1t, b1, QKb, Vtb, nullptr,
                                      1024, 3072);
  k_maskpack<<<65536, 256, 0, stream>>>(mask, mbits);
  k_attn<<<dim3(16, 16, 4), 512, 0, stream>>>(QKb, Vtb, mbits, Ctx);
  k_gemm<1><<<512, 256, 0, stream>>>(Ctx, W2t, b2, nullptr, nullptr, out,
                                     1024, 1024);
}

// Round 19
// 230.667 us; speedup vs baseline: 1.2640x; 1.0258x over previous
//
#include <hip/hip_runtime.h>
#include <hip/hip_bf16.h>
#include <cstdint>

// B=4, L=2048, D=1024, H=16, DK=64
// DELTA vs R18 (green, 236.6us) — two independent tweaks:
//  1. k_attn: mask-word software pipeline (prefetch wd[next] with the stages;
//     hides ~200cyc L2 latency under softmax+PV). Math identical.
//  2. k_gemm: 512-thread blocks (8 waves x 64x32 sub-tiles, same 128^2 tile,
//     same 64KB LDS) -> 16 waves/CU resident, finer interleave over the
//     barrier-drain stalls.
// Blacklist: AND-mask (R9), exp2f (R14), LDS-fat fusion (R16).

typedef __attribute__((ext_vector_type(4))) float f32x4;
typedef __attribute__((ext_vector_type(8))) short s16x8;
typedef __attribute__((ext_vector_type(4))) short s16x4;
typedef __attribute__((ext_vector_type(4))) int   i32x4;

#define AS1 __attribute__((address_space(1)))
#define AS3 __attribute__((address_space(3)))

__device__ __forceinline__ short f2bf(float x) {
  unsigned u = __builtin_bit_cast(unsigned, x);
  unsigned r = u + 0x7fffu + ((u >> 16) & 1u);   // RNE
  return (short)(r >> 16);
}
__device__ __forceinline__ unsigned pack2(float a, float b) {
  // compiler-owned bf16x2 conversion; .x = low word, .y = high word.
  __hip_bfloat162 v = __float22bfloat162_rn(make_float2(a, b));
  unsigned r;
  __builtin_memcpy(&r, &v, 4);
  return r;
}

// ------ fused prep: [0,8192) f32->bf16 convert; [8192,11264) W1 transpose;
// ------ [11264,12288) W2 transpose (transpose+convert to bf16, C x R out)
__global__ __launch_bounds__(256) void k_prep(
    const float* __restrict__ in, short* __restrict__ Xbf,
    const float* __restrict__ W1, short* __restrict__ W1t,
    const float* __restrict__ W2, short* __restrict__ W2t) {
  __shared__ float tile[32][33];
  const int bid = blockIdx.x;
  if (bid < 8192) {                       // convert: 8192*256*4 = 8.39M floats
    int i = bid * 256 + threadIdx.x;
    float4 v = ((const float4*)in)[i];
    s16x4 o;
    o[0] = f2bf(v.x); o[1] = f2bf(v.y); o[2] = f2bf(v.z); o[3] = f2bf(v.w);
    ((s16x4*)Xbf)[i] = o;
    return;
  }
  const float* src; short* dst; int R, C, bx, by;
  if (bid < 11264) { int idx = bid - 8192;  src = W1; dst = W1t; R = 1024; C = 3072; bx = idx % 96; by = idx / 96; }
  else             { int idx = bid - 11264; src = W2; dst = W2t; R = 1024; C = 1024; bx = idx % 32; by = idx / 32; }
  int c0 = bx * 32, r0 = by * 32;
  int tx = threadIdx.x & 31, ty = threadIdx.x >> 5;   // (32,8) roles from 1D
  #pragma unroll
  for (int k = 0; k < 32; k += 8)
    tile[ty + k][tx] = src[(size_t)(r0 + ty + k) * C + c0 + tx];
  __syncthreads();
  #pragma unroll
  for (int k = 0; k < 32; k += 8)
    dst[(size_t)(c0 + ty + k) * R + r0 + tx] = f2bf(tile[tx][ty + k]);
}

// ---------------- mask (int32 0/1) -> bitmask via ballot (no LDS!) ----------
__global__ __launch_bounds__(256) void k_maskpack(const int* __restrict__ mask,
                                                  unsigned* __restrict__ bits) {
  int i = blockIdx.x * 256 + threadIdx.x;
  unsigned long long bal = __ballot(mask[i] != 0);
  int lane = threadIdx.x & 63;
  if (lane == 0)       bits[i >> 5] = (unsigned)bal;
  else if (lane == 32) bits[i >> 5] = (unsigned)(bal >> 32);
}

// ---------------- bf16 MFMA GEMM, A (MxK) row-major, Bt (NxK) row-major ------
// 1D grid, 512 threads = 8 waves, each owning a 64x32 sub-tile of the 128^2
// block tile (wm=(wv&1)*64, wn=(wv>>1)*32). MODE 0: 1536 blocks = QKV proj
// (cols <1024 (Q) scaled 1/8, cols <2048 -> QKbuf, >=2048 -> Vt transposed).
// MODE 1: 512 blocks, output projection -> f32 out, +bias.
// Staging: global_load_lds width=16, pre-swizzled source chunk, double-buffered
// STAGE(next)->compute(cur)->barrier schedule; wave wv stages rows
// [p*64 + wv*8, +8) for p in {0,1}.
template <int MODE>
__global__ __launch_bounds__(512, 4) void k_gemm(
    const short* __restrict__ A, const short* __restrict__ Bt,
    const float* __restrict__ bias,
    short* __restrict__ outQK, short* __restrict__ outVt,
    float* __restrict__ outF, int K, int N) {
  __shared__ short Ast[2][128 * 64];
  __shared__ short Bst[2][128 * 64];
  const int bid = blockIdx.x;
  const int tid = threadIdx.x;
  const int lane = tid & 63;
  const int wv = tid >> 6;                       // 0..7
  const int g = lane >> 4, c = lane & 15;
  const int m0 = (bid & 63) * 128, n0 = (bid >> 6) * 128;
  const int wm = (wv & 1) * 64, wn = (wv >> 1) * 32;

  // staging: wave wv, iter p stages rows [p*64 + wv*8, +8); row&7 == rsub
  const int rsub = lane >> 3;                    // 0..7
  const int cp = (lane & 7) ^ rsub;              // pre-swizzled source chunk
  const short* aSrc = A  + (size_t)(m0 + wv * 8 + rsub) * K + cp * 8;
  const short* bSrc = Bt + (size_t)(n0 + wv * 8 + rsub) * K + cp * 8;

  auto STAGE = [&](int buf, int kt) {
    #pragma unroll
    for (int p = 0; p < 2; ++p) {
      __builtin_amdgcn_global_load_lds(
          (const AS1 void*)(aSrc + (size_t)(p * 64) * K + kt * 64),
          (AS3 void*)&Ast[buf][(p * 64 + wv * 8) * 64], 16, 0, 0);
      __builtin_amdgcn_global_load_lds(
          (const AS1 void*)(bSrc + (size_t)(p * 64) * K + kt * 64),
          (AS3 void*)&Bst[buf][(p * 64 + wv * 8) * 64], 16, 0, 0);
    }
  };

  f32x4 acc[4][2] = {};

  const int nkt = K >> 6;
  STAGE(0, 0);
  __syncthreads();

  #pragma unroll 1
  for (int kt = 0; kt < nkt; ++kt) {
    const int cur = kt & 1;
    if (kt + 1 < nkt) STAGE(cur ^ 1, kt + 1);
    #pragma unroll
    for (int s = 0; s < 2; ++s) {
      s16x8 aF[4], bF[2];
      #pragma unroll
      for (int mi = 0; mi < 4; ++mi) {
        int row = wm + mi * 16 + c;
        aF[mi] = *(const s16x8*)((const char*)&Ast[cur][0] + row * 128 +
                                 ((s * 64 + g * 16) ^ ((row & 7) << 4)));
      }
      #pragma unroll
      for (int ni = 0; ni < 2; ++ni) {
        int row = wn + ni * 16 + c;
        bF[ni] = *(const s16x8*)((const char*)&Bst[cur][0] + row * 128 +
                                 ((s * 64 + g * 16) ^ ((row & 7) << 4)));
      }
      #pragma unroll
      for (int mi = 0; mi < 4; ++mi)
        #pragma unroll
        for (int ni = 0; ni < 2; ++ni)
          acc[mi][ni] = __builtin_amdgcn_mfma_f32_16x16x32_bf16(
              aF[mi], bF[ni], acc[mi][ni], 0, 0, 0);
    }
    __syncthreads();   // drains vmcnt (next tile staged) + all waves done with cur
  }

  #pragma unroll
  for (int mi = 0; mi < 4; ++mi) {
    #pragma unroll
    for (int ni = 0; ni < 2; ++ni) {
      int colg = n0 + wn + ni * 16 + c;
      float bv = bias[colg];
      int rbase = m0 + wm + mi * 16 + 4 * g;   // 4 consecutive rows (4-aligned)
      if (MODE == 0) {
        float sc = (colg < 1024) ? 0.125f : 1.0f;   // fold 1/sqrt(dk) into Q
        if (colg < 2048) {
          #pragma unroll
          for (int r = 0; r < 4; ++r)
            outQK[(size_t)(rbase + r) * 2048 + colg] = f2bf((acc[mi][ni][r] + bv) * sc);
        } else {
          int j = colg - 2048;             // h*64+dk
          int bb = rbase >> 11, lq = rbase & 2047;
          s16x4 pk;
          #pragma unroll
          for (int r = 0; r < 4; ++r) pk[r] = f2bf(acc[mi][ni][r] + bv);
          *(s16x4*)(outVt + (size_t)((bb << 10) + j) * 2048 + lq) = pk;
        }
      } else {
        #pragma unroll
        for (int r = 0; r < 4; ++r)
          outF[(size_t)(rbase + r) * N + colg] = acc[mi][ni][r] + bv;
      }
    }
  }
}

// ---------------- flash attention: 8-wave blocks, K single-buffered ----------
// Grid (L/128, H, B), 8 waves x 16 q-rows = 128 q-rows/block. K is consumed at
// iter top (QK^T) -> single-buffered: QK^T -> barrier A -> STAGE_K(next) +
// STAGE_V(vnxt) + prefetch wd[next] -> softmax/P/PV -> barrier B (drains).
// V double-buffered. LDS 40KB => 4 blocks/CU (2048-thread cap). S^T=mfma(K,Q):
// lane (c,g) holds S[q=c][k=16t+4g+r]. Fixed m=0 softmax; p_num = bt ?
// __expf(s) : 0. Denominator = ones-MFMA rowsum + popcount(masked).
__global__ __launch_bounds__(512) void k_attn(
    const short* __restrict__ QK, const short* __restrict__ Vt,
    const unsigned* __restrict__ mbits, short* __restrict__ ctxb) {
  __shared__ short Klds[64 * 64];        // single-buffered (8 KB)
  __shared__ short Vlds[2][64 * 64];     // double-buffered (16 KB)
  __shared__ short Plds[8][16 * 64];     // per-wave P (16 KB)
  const int tid = threadIdx.x;
  const int lane = tid & 63, wv = tid >> 6;      // wv = 0..7
  const int g = lane >> 4, c = lane & 15;
  const int b = blockIdx.z, h = blockIdx.y;
  const int qr = blockIdx.x * 128 + wv * 16;

  // staging: wave wv stages rows [wv*8, wv*8+8) of each tile (row&7 == rsub)
  const int r0 = wv * 8;
  const int rsub = lane >> 3;                    // 0..7
  const int cp = (lane & 7) ^ rsub;              // pre-swizzled source chunk
  const short* kSrc = QK + (size_t)(b * 2048 + r0 + rsub) * 2048 + 1024 + h * 64 + cp * 8;
  const short* vSrc = Vt + (size_t)((b * 16 + h) * 64 + r0 + rsub) * 2048 + cp * 8;

  auto STAGE_K = [&](int k0) {
    __builtin_amdgcn_global_load_lds((const AS1 void*)(kSrc + (size_t)k0 * 2048),
        (AS3 void*)&Klds[r0 * 64], 16, 0, 0);
  };
  auto STAGE_V = [&](int buf, int k0) {
    __builtin_amdgcn_global_load_lds((const AS1 void*)(vSrc + k0),
        (AS3 void*)&Vlds[buf][r0 * 64], 16, 0, 0);
  };

  s16x8 qf[2];                                    // Q = B-operand fragments
  #pragma unroll
  for (int s = 0; s < 2; ++s)
    qf[s] = *(const s16x8*)(QK + (size_t)(b * 2048 + qr + c) * 2048 +
                            h * 64 + s * 32 + g * 8);

  const unsigned* mptr = mbits + (size_t)(b * 2048 + qr + c) * 64;

  // all-ones bf16 B-operand for the rowsum MFMA
  s16x8 ones;
  #pragma unroll
  for (int i = 0; i < 8; ++i) ones[i] = (short)0x3F80;

  int nm = 0;                       // masked count for q-row c (accumulated)
  f32x4 acc[4] = {};                // ctx[q=4g+r][d=16t+c]
  f32x4 accs = {};                  // rowsum[q=4g+r] of bf16 P (all c equal)
  char* pbase = (char*)&Plds[wv][0];
  const int sw = (c & 7) << 4;

  STAGE_K(0);
  STAGE_V(0, 0);
  uint2 wd = *(const uint2*)(mptr);   // mask words for tile 0
  __syncthreads();

  #pragma unroll 1
  for (int it = 0; it < 32; ++it) {
    const int vcur = it & 1;
    const int k0 = it * 64;

    // ---- S^T = K Q^T : sf[t][r] = S[q=c][k=16t+4g+r] ----
    const char* kb = (const char*)&Klds[0];
    f32x4 sf[4] = {};
    __builtin_amdgcn_s_setprio(1);
    #pragma unroll
    for (int t = 0; t < 4; ++t)
      #pragma unroll
      for (int s = 0; s < 2; ++s) {
        s16x8 kf = *(const s16x8*)(kb + (16 * t + c) * 128 + ((g * 16 + s * 64) ^ sw));
        sf[t] = __builtin_amdgcn_mfma_f32_16x16x32_bf16(kf, qf[s], sf[t], 0, 0, 0);
      }
    __builtin_amdgcn_s_setprio(0);

    __syncthreads();   // barrier A: all waves done reading Klds (nothing to drain)
    uint2 wdn = wd;
    if (it < 31) {
      STAGE_K(k0 + 64);             // overwrite Klds: safe, post-barrier-A
      STAGE_V(vcur ^ 1, k0 + 64);
      wdn = *(const uint2*)(mptr + ((k0 + 64) >> 5));   // prefetch next mask
    }

    nm += 64 - __popc(wd.x) - __popc(wd.y);      // masked keys this tile
    unsigned w0 = wd.x >> (4 * g), w1 = wd.y >> (4 * g);
    // ---- p_num = bt ? exp(s) : 0 ; masked handled via nm in denominator ----
    #pragma unroll
    for (int t = 0; t < 4; ++t) {
      unsigned w = (t < 2) ? w0 : w1;
      int sh = 16 * (t & 1);
      float p[4];
      #pragma unroll
      for (int r = 0; r < 4; ++r) {
        unsigned bt = (w >> (sh + r)) & 1u;
        p[r] = bt ? __expf(sf[t][r]) : 0.0f;     // masked -> 0 in numerator
      }
      unsigned lo = pack2(p[0], p[1]);
      unsigned hi = pack2(p[2], p[3]);
      *(uint2*)(pbase + c * 128 + ((t * 32 + g * 8) ^ sw)) = make_uint2(lo, hi);
    }
    asm volatile("" ::: "memory");   // keep P writes before P reads
    // ---- ctx += P V ; denom += P ones ----
    s16x8 pa[2];
    #pragma unroll
    for (int s = 0; s < 2; ++s)
      pa[s] = *(const s16x8*)(pbase + c * 128 + ((s * 64 + g * 16) ^ sw));
    const char* vb = (const char*)&Vlds[vcur][0];
    __builtin_amdgcn_s_setprio(1);
    accs = __builtin_amdgcn_mfma_f32_16x16x32_bf16(pa[0], ones, accs, 0, 0, 0);
    accs = __builtin_amdgcn_mfma_f32_16x16x32_bf16(pa[1], ones, accs, 0, 0, 0);
    #pragma unroll
    for (int t = 0; t < 4; ++t)
      #pragma unroll
      for (int s = 0; s < 2; ++s) {
        s16x8 vf = *(const s16x8*)(vb + (16 * t + c) * 128 + ((g * 16 + s * 64) ^ sw));
        acc[t] = __builtin_amdgcn_mfma_f32_16x16x32_bf16(pa[s], vf, acc[t], 0, 0, 0);
      }
    __builtin_amdgcn_s_setprio(0);
    wd = wdn;
    __syncthreads();   // barrier B: drains K/V stages; all waves done with vcur
  }

  // ---- epilogue: denom[q=4g+r] = accs[r] + nm(from lane q=4g+r) ----
  float nmf = (float)nm;
  float lv[4];
  #pragma unroll
  for (int r = 0; r < 4; ++r)
    lv[r] = 1.0f / (accs[r] + __shfl(nmf, 4 * g + r));
  #pragma unroll
  for (int t = 0; t < 4; ++t)
    #pragma unroll
    for (int r = 0; r < 4; ++r)
      ctxb[(size_t)(b * 2048 + qr + 4 * g + r) * 1024 + h * 64 + t * 16 + c] =
          f2bf(acc[t][r] * lv[r]);
}

extern "C" void kernel_launch(void* const* d_in, const int* in_sizes, int n_in,
                              void* d_out, int out_size, void* d_ws, size_t ws_size,
                              hipStream_t stream) {
  const float* inputs = (const float*)d_in[0];   // (4,2048,1024) f32
  const int*   mask   = (const int*)  d_in[1];   // (4,2048,2048) int32
  const float* W1     = (const float*)d_in[2];   // (1024,3072) f32
  const float* b1     = (const float*)d_in[3];   // (3072,) f32
  const float* W2     = (const float*)d_in[4];   // (1024,1024) f32
  const float* b2     = (const float*)d_in[5];   // (1024,) f32
  float* out = (float*)d_out;                    // (4,2048,1024) f32

  char* ws = (char*)d_ws;
  short* Xbf = (short*)ws;        ws += (size_t)8192 * 1024 * 2;   // 16.78 MB
  short* W1t = (short*)ws;        ws += (size_t)3072 * 1024 * 2;   //  6.29 MB
  short* W2t = (short*)ws;        ws += (size_t)1024 * 1024 * 2;   //  2.10 MB
  short* QKb = (short*)ws;        ws += (size_t)8192 * 2048 * 2;   // 33.55 MB
  short* Vtb = (short*)ws;        ws += (size_t)4096 * 2048 * 2;   // 16.78 MB
  short* Ctx = (short*)ws;        ws += (size_t)8192 * 1024 * 2;   // 16.78 MB
  unsigned* mbits = (unsigned*)ws; ws += (size_t)4 * 2048 * 64 * 4; // 2.10 MB
  // total ~94.4 MB of d_ws

  k_prep<<<12288, 256, 0, stream>>>(inputs, Xbf, W1, W1t, W2, W2t);
  k_gemm<0><<<1536, 512, 0, stream>>>(Xbf, W1t, b1, QKb, Vtb, nullptr,
                                      1024, 3072);
  k_maskpack<<<65536, 256, 0, stream>>>(mask, mbits);
  k_attn<<<dim3(16, 16, 4), 512, 0, stream>>>(QKb, Vtb, mbits, Ctx);
  k_gemm<1><<<512, 512, 0, stream>>>(Ctx, W2t, b2, nullptr, nullptr, out,
                                     1024, 1024);
}